// Round 2
// baseline (495.992 us; speedup 1.0000x reference)
//
#include <hip/hip_runtime.h>
#include <math.h>

// ---------------------------------------------------------------------------
// MoE top-2 of 8 experts, H=768, I=1536, T=2048 tokens.
// Input dtype (fp32 vs bf16) detected at runtime from x's bit patterns; all
// compute runs through bf16 MFMA (16x16x32) with fp32 accumulation.
//   detect -> init -> convert x / convert+transpose W -> router -> prefix ->
//   scatter (counting sort, 64-padded expert regions) ->
//   GEMM1 act=silu(X Wg)*(X Wu) -> GEMM2 y=p*(act Wd) -> combine
// All data-dependent indices are clamped: worst case = wrong numbers, never
// a wild address (round-1 SIGABRT was a wild scatter write from NaN logits).
// ---------------------------------------------------------------------------

typedef unsigned short u16;
typedef __attribute__((ext_vector_type(8))) short bhalf8;   // 8 bf16 (4 VGPRs)
typedef __attribute__((ext_vector_type(4))) float floatx4;  // MFMA C/D

#define HD 768
#define ID 1536
#define NE 8
#define TT 2048
#define KTOP 2
#define SLOTS 4608  // 4096 assignments + per-expert pad to 64

__device__ __forceinline__ float b2f(u16 u) {
    union { unsigned int i; float f; } v; v.i = ((unsigned int)u) << 16; return v.f;
}
__device__ __forceinline__ u16 f2b(float f) {
    union { float f; unsigned int i; } v; v.f = f;
    unsigned int i = v.i;
    return (u16)((i + 0x7FFFu + ((i >> 16) & 1u)) >> 16);  // RNE
}

// ---- dtype sniffing: bf16 data -> nearly all words have sane exponents ----
__global__ void detect_k(const u16* __restrict__ x16, int* flag) {
    int lane = threadIdx.x;  // 64
    int c = 0;
#pragma unroll
    for (int j = 0; j < 4; ++j) {
        u16 w = x16[lane + 64 * j];
        int ex = (w >> 7) & 0xFF;
        c += (ex >= 118 && ex <= 135);  // |v| in [2^-9, 2^9)
    }
#pragma unroll
    for (int off = 32; off > 0; off >>= 1) c += __shfl_xor(c, off);
    if (lane == 0) *flag = (c >= 200) ? 1 : 0;  // fp32 scores ~136, bf16 ~255
}

__global__ void init_k(int* hdr, int* tokof, float* pslot) {
    int i = blockIdx.x * 256 + threadIdx.x;
    if (i < 40) hdr[i] = 0;  // cnt/cursor/base/total/probsum (bytes 0..160)
    if (i < SLOTS) { tokof[i] = -1; pslot[i] = 0.f; }
}

// ---- x -> bf16 (copy-through if already bf16) ----
__global__ void xcvt_k(const void* __restrict__ src, u16* __restrict__ dst,
                       const int* __restrict__ flag) {
    int i = (blockIdx.x * 256 + threadIdx.x) * 8;
    if (*flag) {
        *(uint4*)&dst[i] = *(const uint4*)((const u16*)src + i);
    } else {
        const float* s = (const float*)src;
        float4 v0 = *(const float4*)&s[i];
        float4 v1 = *(const float4*)&s[i + 4];
        union { uint4 v; u16 u[8]; } o;
        o.u[0] = f2b(v0.x); o.u[1] = f2b(v0.y); o.u[2] = f2b(v0.z); o.u[3] = f2b(v0.w);
        o.u[4] = f2b(v1.x); o.u[5] = f2b(v1.y); o.u[6] = f2b(v1.z); o.u[7] = f2b(v1.w);
        *(uint4*)&dst[i] = o.v;
    }
}

// ---- W [E][R][C] (fp32 or bf16) -> bf16 transposed [E][C][R] ----
__global__ void cvtT_k(const void* __restrict__ src, u16* __restrict__ dst,
                       int R, int C, const int* __restrict__ flag) {
    __shared__ u16 tile[64][72];
    int e = blockIdx.z;
    int r0 = blockIdx.y * 64, c0 = blockIdx.x * 64;
    int t = threadIdx.x;
    if (*flag) {
        const u16* s = (const u16*)src + (size_t)e * R * C;
        int r = t >> 3, cg = (t & 7) * 8;
        *(uint4*)&tile[r][cg]      = *(const uint4*)&s[(size_t)(r0 + r) * C + c0 + cg];
        *(uint4*)&tile[r + 32][cg] = *(const uint4*)&s[(size_t)(r0 + r + 32) * C + c0 + cg];
    } else {
        const float* s = (const float*)src + (size_t)e * R * C;
        int r = t >> 2, c4 = (t & 3) * 16;
#pragma unroll
        for (int j = 0; j < 4; ++j) {
            float4 v = *(const float4*)&s[(size_t)(r0 + r) * C + c0 + c4 + 4 * j];
            ushort4 o;
            o.x = f2b(v.x); o.y = f2b(v.y); o.z = f2b(v.z); o.w = f2b(v.w);
            *(ushort4*)&tile[r][c4 + 4 * j] = o;
        }
    }
    __syncthreads();
    u16* d = dst + (size_t)e * R * C;
    int c = t >> 3, rg = (t & 7) * 8;
    union { uint4 v; u16 u[8]; } o;
#pragma unroll
    for (int j = 0; j < 8; ++j) o.u[j] = tile[rg + j][c];
    *(uint4*)&d[(size_t)(c0 + c) * R + r0 + rg] = o.v;
#pragma unroll
    for (int j = 0; j < 8; ++j) o.u[j] = tile[rg + j][c + 32];
    *(uint4*)&d[(size_t)(c0 + c + 32) * R + r0 + rg] = o.v;
}

// ---- router: one wave per token, full-precision reads ----
__global__ void router_k(const void* __restrict__ x, const void* __restrict__ rw,
                         const int* __restrict__ flag,
                         int* cnt, float* probsum, int* topki, float* topkp) {
    int lane = threadIdx.x & 63;
    int t = blockIdx.x * 4 + (threadIdx.x >> 6);
    int bf = *flag;
    const float* xf = (const float*)x + (size_t)t * HD;
    const u16*   xh = (const u16*)x + (size_t)t * HD;
    const float* rf = (const float*)rw;
    const u16*   rh = (const u16*)rw;
    float acc[NE];
#pragma unroll
    for (int e = 0; e < NE; ++e) acc[e] = 0.f;
    for (int j = 0; j < HD / 64; ++j) {
        int h = lane + 64 * j;
        float xv = bf ? b2f(xh[h]) : xf[h];
#pragma unroll
        for (int e = 0; e < NE; ++e)
            acc[e] += xv * (bf ? b2f(rh[h * NE + e]) : rf[h * NE + e]);
    }
#pragma unroll
    for (int e = 0; e < NE; ++e) {
        float v = acc[e];
#pragma unroll
        for (int off = 32; off > 0; off >>= 1) v += __shfl_xor(v, off);
        acc[e] = v;
    }
    if (lane == 0) {
        float m = acc[0];
        for (int e = 1; e < NE; ++e) m = fmaxf(m, acc[e]);
        float p[NE], s = 0.f;
        for (int e = 0; e < NE; ++e) { p[e] = expf(acc[e] - m); s += p[e]; }
        float inv = 1.f / s;
        for (int e = 0; e < NE; ++e) p[e] *= inv;
        int i1 = 0; float p1 = p[0];
        for (int e = 1; e < NE; ++e) if (p[e] > p1) { p1 = p[e]; i1 = e; }  // first-max (jax tie rule)
        int i2 = -1; float p2 = -1.f;
        for (int e = 0; e < NE; ++e) if (e != i1 && p[e] > p2) { p2 = p[e]; i2 = e; }
        if (i2 < 0) { i2 = (i1 + 1) & 7; p2 = p[i2]; }  // NaN guard
        float sn = 1.f / (p1 + p2);
        topki[2 * t] = i1;  topki[2 * t + 1] = i2;
        topkp[2 * t] = p1 * sn;  topkp[2 * t + 1] = p2 * sn;
        for (int e = 0; e < NE; ++e) atomicAdd(&probsum[e], p[e]);
        atomicAdd(&cnt[i1], 1); atomicAdd(&cnt[i2], 1);
    }
}

// ---- prefix over 8 experts (64-padded) + aux loss ----
__global__ void prefix_k(const int* cnt, const float* probsum, int* base,
                         int* total, int* cursor, void* out, const int* flag) {
    if (threadIdx.x == 0) {
        int cum = 0; float aux = 0.f;
        for (int e = 0; e < NE; ++e) {
            int c = cnt[e];
            base[e] = cum; cum += (c + 63) & ~63;
            cursor[e] = 0;
            aux += ((float)c / (float)(TT * KTOP)) * (probsum[e] / (float)TT);
        }
        *total = cum;
        float auxv = aux * (float)NE * 0.01f;
        if (*flag) ((u16*)out)[(size_t)TT * HD] = f2b(auxv);
        else       ((float*)out)[(size_t)TT * HD] = auxv;
    }
}

// ---- scatter tokens into per-expert slot regions (clamped) ----
__global__ void scatter_k(const int* __restrict__ topki, const float* __restrict__ topkp,
                          const int* __restrict__ base, int* cursor,
                          int* tokof, float* pslot, int* slotmap) {
    int t = blockIdx.x * blockDim.x + threadIdx.x;
    if (t >= TT) return;
#pragma unroll
    for (int k = 0; k < KTOP; ++k) {
        int e = topki[2 * t + k] & 7;
        int pos = atomicAdd(&cursor[e], 1);
        int slot = base[e] + pos;
        slot = min(max(slot, 0), SLOTS - 1);
        tokof[slot] = t;
        pslot[slot] = topkp[2 * t + k];
        slotmap[2 * t + k] = slot;
    }
}

// ---- GEMM1: act = silu(X Wg) * (X Wu); 64x64 tile, 4 waves of 32x32 ----
__global__ __launch_bounds__(256) void gemm1_k(
        const u16* __restrict__ xb, const u16* __restrict__ wgt,
        const u16* __restrict__ wut, const int* __restrict__ base,
        const int* __restrict__ total, const int* __restrict__ tokof,
        u16* __restrict__ act) {
    __shared__ u16 As[64][72], Bg[64][72], Bu[64][72];
    int row0 = blockIdx.y * 64;
    if (row0 >= *total) return;
    int e = 7;
    while (e > 0 && row0 < base[e]) --e;
    int n0 = blockIdx.x * 64;
    int tid = threadIdx.x;
    int r = tid >> 2, cg = (tid & 3) * 8;
    int tok = tokof[row0 + r];
    bool tv = ((unsigned)tok < (unsigned)TT);
    const u16* xrow = xb + (size_t)(tv ? tok : 0) * HD;
    const u16* bgrow = wgt + ((size_t)e * ID + n0 + r) * HD;
    const u16* burow = wut + ((size_t)e * ID + n0 + r) * HD;
    int wave = tid >> 6, lane = tid & 63;
    int wm = (wave & 1) * 32, wn = (wave >> 1) * 32;
    int lhi = (lane >> 4) * 8, llo = lane & 15;
    floatx4 accG[2][2], accU[2][2];
#pragma unroll
    for (int i = 0; i < 2; ++i)
#pragma unroll
        for (int j = 0; j < 2; ++j) {
            accG[i][j] = floatx4{0.f, 0.f, 0.f, 0.f};
            accU[i][j] = floatx4{0.f, 0.f, 0.f, 0.f};
        }
    uint4 z4 = make_uint4(0, 0, 0, 0);
    for (int k0 = 0; k0 < HD; k0 += 64) {
        uint4 a1 = z4, a2 = z4;
        if (tv) {
            a1 = *(const uint4*)&xrow[k0 + cg];
            a2 = *(const uint4*)&xrow[k0 + cg + 32];
        }
        uint4 g1 = *(const uint4*)&bgrow[k0 + cg];
        uint4 g2 = *(const uint4*)&bgrow[k0 + cg + 32];
        uint4 u1 = *(const uint4*)&burow[k0 + cg];
        uint4 u2 = *(const uint4*)&burow[k0 + cg + 32];
        __syncthreads();
        *(uint4*)&As[r][cg] = a1; *(uint4*)&As[r][cg + 32] = a2;
        *(uint4*)&Bg[r][cg] = g1; *(uint4*)&Bg[r][cg + 32] = g2;
        *(uint4*)&Bu[r][cg] = u1; *(uint4*)&Bu[r][cg + 32] = u2;
        __syncthreads();
#pragma unroll
        for (int kk = 0; kk < 64; kk += 32) {
            bhalf8 a0 = *(const bhalf8*)&As[wm + llo][kk + lhi];
            bhalf8 a1f = *(const bhalf8*)&As[wm + 16 + llo][kk + lhi];
            bhalf8 b0 = *(const bhalf8*)&Bg[wn + llo][kk + lhi];
            bhalf8 b1 = *(const bhalf8*)&Bg[wn + 16 + llo][kk + lhi];
            bhalf8 c0 = *(const bhalf8*)&Bu[wn + llo][kk + lhi];
            bhalf8 c1 = *(const bhalf8*)&Bu[wn + 16 + llo][kk + lhi];
            accG[0][0] = __builtin_amdgcn_mfma_f32_16x16x32_bf16(a0, b0, accG[0][0], 0, 0, 0);
            accG[0][1] = __builtin_amdgcn_mfma_f32_16x16x32_bf16(a0, b1, accG[0][1], 0, 0, 0);
            accG[1][0] = __builtin_amdgcn_mfma_f32_16x16x32_bf16(a1f, b0, accG[1][0], 0, 0, 0);
            accG[1][1] = __builtin_amdgcn_mfma_f32_16x16x32_bf16(a1f, b1, accG[1][1], 0, 0, 0);
            accU[0][0] = __builtin_amdgcn_mfma_f32_16x16x32_bf16(a0, c0, accU[0][0], 0, 0, 0);
            accU[0][1] = __builtin_amdgcn_mfma_f32_16x16x32_bf16(a0, c1, accU[0][1], 0, 0, 0);
            accU[1][0] = __builtin_amdgcn_mfma_f32_16x16x32_bf16(a1f, c0, accU[1][0], 0, 0, 0);
            accU[1][1] = __builtin_amdgcn_mfma_f32_16x16x32_bf16(a1f, c1, accU[1][1], 0, 0, 0);
        }
    }
    int mrow = (lane >> 4) * 4;  // C/D: col=lane&15, row=(lane>>4)*4+reg
#pragma unroll
    for (int i = 0; i < 2; ++i)
#pragma unroll
        for (int j = 0; j < 2; ++j)
#pragma unroll
            for (int rr = 0; rr < 4; ++rr) {
                int m = row0 + wm + i * 16 + mrow + rr;
                int n = n0 + wn + j * 16 + llo;
                float g = accG[i][j][rr], u = accU[i][j][rr];
                float sv = g / (1.f + expf(-g));
                act[(size_t)m * ID + n] = f2b(sv * u);
            }
}

// ---- GEMM2: y = p * (act Wd), fp32 out ----
__global__ __launch_bounds__(256) void gemm2_k(
        const u16* __restrict__ act, const u16* __restrict__ wdt,
        const int* __restrict__ base, const int* __restrict__ total,
        const float* __restrict__ pslot, float* __restrict__ y) {
    __shared__ u16 As[64][72], Bs[64][72];
    int row0 = blockIdx.y * 64;
    if (row0 >= *total) return;
    int e = 7;
    while (e > 0 && row0 < base[e]) --e;
    int n0 = blockIdx.x * 64;
    int tid = threadIdx.x;
    int r = tid >> 2, cg = (tid & 3) * 8;
    const u16* arow = act + (size_t)(row0 + r) * ID;
    const u16* brow = wdt + ((size_t)e * HD + n0 + r) * ID;
    int wave = tid >> 6, lane = tid & 63;
    int wm = (wave & 1) * 32, wn = (wave >> 1) * 32;
    int lhi = (lane >> 4) * 8, llo = lane & 15;
    floatx4 acc[2][2];
#pragma unroll
    for (int i = 0; i < 2; ++i)
#pragma unroll
        for (int j = 0; j < 2; ++j) acc[i][j] = floatx4{0.f, 0.f, 0.f, 0.f};
    for (int k0 = 0; k0 < ID; k0 += 64) {
        uint4 a1 = *(const uint4*)&arow[k0 + cg];
        uint4 a2 = *(const uint4*)&arow[k0 + cg + 32];
        uint4 b1 = *(const uint4*)&brow[k0 + cg];
        uint4 b2 = *(const uint4*)&brow[k0 + cg + 32];
        __syncthreads();
        *(uint4*)&As[r][cg] = a1; *(uint4*)&As[r][cg + 32] = a2;
        *(uint4*)&Bs[r][cg] = b1; *(uint4*)&Bs[r][cg + 32] = b2;
        __syncthreads();
#pragma unroll
        for (int kk = 0; kk < 64; kk += 32) {
            bhalf8 a0 = *(const bhalf8*)&As[wm + llo][kk + lhi];
            bhalf8 a1f = *(const bhalf8*)&As[wm + 16 + llo][kk + lhi];
            bhalf8 b0 = *(const bhalf8*)&Bs[wn + llo][kk + lhi];
            bhalf8 b1f = *(const bhalf8*)&Bs[wn + 16 + llo][kk + lhi];
            acc[0][0] = __builtin_amdgcn_mfma_f32_16x16x32_bf16(a0, b0, acc[0][0], 0, 0, 0);
            acc[0][1] = __builtin_amdgcn_mfma_f32_16x16x32_bf16(a0, b1f, acc[0][1], 0, 0, 0);
            acc[1][0] = __builtin_amdgcn_mfma_f32_16x16x32_bf16(a1f, b0, acc[1][0], 0, 0, 0);
            acc[1][1] = __builtin_amdgcn_mfma_f32_16x16x32_bf16(a1f, b1f, acc[1][1], 0, 0, 0);
        }
    }
    int mrow = (lane >> 4) * 4;
#pragma unroll
    for (int i = 0; i < 2; ++i)
#pragma unroll
        for (int j = 0; j < 2; ++j)
#pragma unroll
            for (int rr = 0; rr < 4; ++rr) {
                int m = row0 + wm + i * 16 + mrow + rr;
                int n = n0 + wn + j * 16 + llo;
                float p = pslot[m];  // init'd to 0 -> padded rows exactly 0
                y[(size_t)m * HD + n] = p * acc[i][j][rr];
            }
}

// ---- combine the two expert slots per token; dtype-flagged output ----
__global__ void combine_k(const float* __restrict__ y, const int* __restrict__ slotmap,
                          void* __restrict__ out, const int* __restrict__ flag) {
    int g = blockIdx.x * 256 + threadIdx.x;  // TT*192 quads
    int t = g / 192;
    int q = (g % 192) * 4;
    int s0 = slotmap[2 * t], s1 = slotmap[2 * t + 1];
    s0 = min(max(s0, 0), SLOTS - 1);
    s1 = min(max(s1, 0), SLOTS - 1);
    float4 a = *(const float4*)&y[(size_t)s0 * HD + q];
    float4 b = *(const float4*)&y[(size_t)s1 * HD + q];
    float4 rv;
    rv.x = a.x + b.x; rv.y = a.y + b.y; rv.z = a.z + b.z; rv.w = a.w + b.w;
    if (*flag) {
        ushort4 o;
        o.x = f2b(rv.x); o.y = f2b(rv.y); o.z = f2b(rv.z); o.w = f2b(rv.w);
        *(ushort4*)((u16*)out + (size_t)t * HD + q) = o;
    } else {
        *(float4*)((float*)out + (size_t)t * HD + q) = rv;
    }
}

extern "C" void kernel_launch(void* const* d_in, const int* in_sizes, int n_in,
                              void* d_out, int out_size, void* d_ws, size_t ws_size,
                              hipStream_t stream) {
    const void* x  = d_in[0];
    const void* rw = d_in[1];
    const void* wg = d_in[2];
    const void* wu = d_in[3];
    const void* wd = d_in[4];
    char* ws = (char*)d_ws;

    // workspace layout (bytes); total 88,166,656
    int*   hdr     = (int*)(ws + 0);        // cnt[8],cursor[8],base[8],total,probsum[8]
    int*   cnt     = (int*)(ws + 0);
    int*   cursor  = (int*)(ws + 32);
    int*   base    = (int*)(ws + 64);
    int*   total   = (int*)(ws + 96);
    float* probsum = (float*)(ws + 128);
    int*   flag    = (int*)(ws + 224);
    int*   topki   = (int*)(ws + 256);        // [4096]
    float* topkp   = (float*)(ws + 16640);    // [4096]
    int*   tokof   = (int*)(ws + 33024);      // [4608]
    float* pslot   = (float*)(ws + 51456);    // [4608]
    int*   slotmap = (int*)(ws + 69888);      // [4096]
    u16*   xb      = (u16*)(ws + 86272);      // [2048*768] bf16
    u16*   act     = (u16*)(ws + 3232000);    // [4608*1536] bf16
    float* ybuf    = (float*)(ws + 17387776); // [4608*768] fp32
    u16*   wgt     = (u16*)(ws + 31543552);   // [8][1536][768] bf16
    u16*   wut     = (u16*)(ws + 50417920);
    u16*   wdt     = (u16*)(ws + 69292288);   // [8][768][1536] bf16
    if (ws_size < 88166656u) return;  // clean absmax-fail beats a wild write

    detect_k<<<1, 64, 0, stream>>>((const u16*)x, flag);
    init_k<<<18, 256, 0, stream>>>(hdr, tokof, pslot);
    xcvt_k<<<(TT * HD / 8) / 256, 256, 0, stream>>>(x, xb, flag);
    cvtT_k<<<dim3(ID / 64, HD / 64, NE), 256, 0, stream>>>(wg, wgt, HD, ID, flag);
    cvtT_k<<<dim3(ID / 64, HD / 64, NE), 256, 0, stream>>>(wu, wut, HD, ID, flag);
    cvtT_k<<<dim3(HD / 64, ID / 64, NE), 256, 0, stream>>>(wd, wdt, ID, HD, flag);
    router_k<<<TT / 4, 256, 0, stream>>>(x, rw, flag, cnt, probsum, topki, topkp);
    prefix_k<<<1, 64, 0, stream>>>(cnt, probsum, base, total, cursor, d_out, flag);
    scatter_k<<<TT / 256, 256, 0, stream>>>(topki, topkp, base, cursor,
                                            tokof, pslot, slotmap);
    gemm1_k<<<dim3(ID / 64, SLOTS / 64), 256, 0, stream>>>(xb, wgt, wut, base, total,
                                                           tokof, act);
    gemm2_k<<<dim3(HD / 64, SLOTS / 64), 256, 0, stream>>>(act, wdt, base, total,
                                                           pslot, ybuf);
    combine_k<<<(TT * 192) / 256, 256, 0, stream>>>(ybuf, slotmap, d_out, flag);
}

// Round 3
// 270.542 us; speedup vs baseline: 1.8333x; 1.8333x over previous
//
#include <hip/hip_runtime.h>
#include <math.h>

// ---------------------------------------------------------------------------
// MoE top-2 of 8 experts, H=768, I=1536, T=2048 tokens.
// Input dtype (fp32 vs bf16) detected at runtime; compute via bf16 MFMA.
//   init(+detect) -> xcvt -> cvtT(wg+wu) -> cvtT(wd) -> router -> prefix ->
//   scatter -> GEMM1 silu(XWg)*(XWu) -> GEMM2 p*(act Wd) -> combine
// R2 fix: router had 16K contended atomics on 8 addresses (249 us, VALUBusy
// 0.7%). Replaced with block-LDS reduction + single-block histogram; scatter
// uses two-level counting sort (64 global atomics total).
// ---------------------------------------------------------------------------

typedef unsigned short u16;
typedef __attribute__((ext_vector_type(8))) short bhalf8;   // 8 bf16 (4 VGPRs)
typedef __attribute__((ext_vector_type(4))) float floatx4;  // MFMA C/D

#define HD 768
#define ID 1536
#define NE 8
#define TT 2048
#define KTOP 2
#define SLOTS 4608   // 4096 assignments + per-expert pad to 64
#define RBLK 512     // router blocks (TT/4)

__device__ __forceinline__ float b2f(u16 u) {
    union { unsigned int i; float f; } v; v.i = ((unsigned int)u) << 16; return v.f;
}
__device__ __forceinline__ u16 f2b(float f) {
    union { float f; unsigned int i; } v; v.f = f;
    unsigned int i = v.i;
    return (u16)((i + 0x7FFFu + ((i >> 16) & 1u)) >> 16);  // RNE
}

// ---- init + dtype sniff (block 0 wave 0 classifies x's bit patterns) ----
__global__ void init_k(const u16* __restrict__ x16, int* flag,
                       int* hdr, int* tokof, float* pslot) {
    int i = blockIdx.x * 256 + threadIdx.x;
    if (i < 40) hdr[i] = 0;  // cnt/cursor/base/total/probsum
    if (i < SLOTS) { tokof[i] = -1; pslot[i] = 0.f; }
    if (blockIdx.x == 0 && threadIdx.x < 64) {
        int lane = threadIdx.x, c = 0;
#pragma unroll
        for (int j = 0; j < 4; ++j) {
            u16 w = x16[lane + 64 * j];
            int ex = (w >> 7) & 0xFF;
            c += (ex >= 118 && ex <= 135);  // bf16 data ~255/256, fp32 ~136
        }
#pragma unroll
        for (int off = 32; off > 0; off >>= 1) c += __shfl_xor(c, off);
        if (lane == 0) *flag = (c >= 200) ? 1 : 0;
    }
}

// ---- x -> bf16 (copy-through if already bf16) ----
__global__ void xcvt_k(const void* __restrict__ src, u16* __restrict__ dst,
                       const int* __restrict__ flag) {
    int i = (blockIdx.x * 256 + threadIdx.x) * 8;
    if (*flag) {
        *(uint4*)&dst[i] = *(const uint4*)((const u16*)src + i);
    } else {
        const float* s = (const float*)src;
        float4 v0 = *(const float4*)&s[i];
        float4 v1 = *(const float4*)&s[i + 4];
        union { uint4 v; u16 u[8]; } o;
        o.u[0] = f2b(v0.x); o.u[1] = f2b(v0.y); o.u[2] = f2b(v0.z); o.u[3] = f2b(v0.w);
        o.u[4] = f2b(v1.x); o.u[5] = f2b(v1.y); o.u[6] = f2b(v1.z); o.u[7] = f2b(v1.w);
        *(uint4*)&dst[i] = o.v;
    }
}

// ---- W [E][R][C] (fp32 or bf16) -> bf16 transposed [E][C][R] ----
// srcB selects between two tensors so wg+wu share one launch (z in [0,16)).
__global__ void cvtT_k(const void* __restrict__ srcA, const void* __restrict__ srcB,
                       u16* __restrict__ dstA, u16* __restrict__ dstB,
                       int R, int C, const int* __restrict__ flag) {
    __shared__ u16 tile[64][72];
    int z = blockIdx.z;
    const void* src = (z < NE || srcB == nullptr) ? srcA : srcB;
    u16* dst = (z < NE || dstB == nullptr) ? dstA : dstB;
    int e = z & (NE - 1);
    int r0 = blockIdx.y * 64, c0 = blockIdx.x * 64;
    int t = threadIdx.x;
    if (*flag) {
        const u16* s = (const u16*)src + (size_t)e * R * C;
        int r = t >> 3, cg = (t & 7) * 8;
        *(uint4*)&tile[r][cg]      = *(const uint4*)&s[(size_t)(r0 + r) * C + c0 + cg];
        *(uint4*)&tile[r + 32][cg] = *(const uint4*)&s[(size_t)(r0 + r + 32) * C + c0 + cg];
    } else {
        const float* s = (const float*)src + (size_t)e * R * C;
        int r = t >> 2, c4 = (t & 3) * 16;
#pragma unroll
        for (int j = 0; j < 4; ++j) {
            float4 v = *(const float4*)&s[(size_t)(r0 + r) * C + c0 + c4 + 4 * j];
            ushort4 o;
            o.x = f2b(v.x); o.y = f2b(v.y); o.z = f2b(v.z); o.w = f2b(v.w);
            *(ushort4*)&tile[r][c4 + 4 * j] = o;
        }
    }
    __syncthreads();
    u16* d = dst + (size_t)e * R * C;
    int c = t >> 3, rg = (t & 7) * 8;
    union { uint4 v; u16 u[8]; } o;
#pragma unroll
    for (int j = 0; j < 8; ++j) o.u[j] = tile[rg + j][c];
    *(uint4*)&d[(size_t)(c0 + c) * R + r0 + rg] = o.v;
#pragma unroll
    for (int j = 0; j < 8; ++j) o.u[j] = tile[rg + j][c + 32];
    *(uint4*)&d[(size_t)(c0 + c + 32) * R + r0 + rg] = o.v;
}

// ---- router: one wave per token; atomic-free (block partials to global) ----
__global__ void router_k(const void* __restrict__ x, const void* __restrict__ rw,
                         const int* __restrict__ flag,
                         int* topki, float* topkp, float* blockpart) {
    __shared__ float sp[4][NE];
    int lane = threadIdx.x & 63;
    int wave = threadIdx.x >> 6;
    int t = blockIdx.x * 4 + wave;
    int bf = *flag;
    const float* xf = (const float*)x + (size_t)t * HD;
    const u16*   xh = (const u16*)x + (size_t)t * HD;
    const float* rf = (const float*)rw;
    const u16*   rh = (const u16*)rw;
    float acc[NE];
#pragma unroll
    for (int e = 0; e < NE; ++e) acc[e] = 0.f;
    for (int j = 0; j < HD / 64; ++j) {
        int h = lane + 64 * j;
        float xv = bf ? b2f(xh[h]) : xf[h];
#pragma unroll
        for (int e = 0; e < NE; ++e)
            acc[e] += xv * (bf ? b2f(rh[h * NE + e]) : rf[h * NE + e]);
    }
#pragma unroll
    for (int e = 0; e < NE; ++e) {
        float v = acc[e];
#pragma unroll
        for (int off = 32; off > 0; off >>= 1) v += __shfl_xor(v, off);
        acc[e] = v;
    }
    if (lane == 0) {
        float m = acc[0];
        for (int e = 1; e < NE; ++e) m = fmaxf(m, acc[e]);
        float p[NE], s = 0.f;
        for (int e = 0; e < NE; ++e) { p[e] = expf(acc[e] - m); s += p[e]; }
        float inv = 1.f / s;
        for (int e = 0; e < NE; ++e) { p[e] *= inv; sp[wave][e] = p[e]; }
        int i1 = 0; float p1 = p[0];
        for (int e = 1; e < NE; ++e) if (p[e] > p1) { p1 = p[e]; i1 = e; }  // first-max
        int i2 = -1; float p2 = -1.f;
        for (int e = 0; e < NE; ++e) if (e != i1 && p[e] > p2) { p2 = p[e]; i2 = e; }
        if (i2 < 0) { i2 = (i1 + 1) & 7; p2 = p[i2]; }  // NaN guard
        float sn = 1.f / (p1 + p2);
        topki[2 * t] = i1;  topki[2 * t + 1] = i2;
        topkp[2 * t] = p1 * sn;  topkp[2 * t + 1] = p2 * sn;
    }
    __syncthreads();
    if (threadIdx.x < NE) {
        float v = sp[0][threadIdx.x] + sp[1][threadIdx.x] +
                  sp[2][threadIdx.x] + sp[3][threadIdx.x];
        blockpart[blockIdx.x * NE + threadIdx.x] = v;
    }
}

// ---- prefix: histogram topki + reduce partials + bases + aux (1 block) ----
__global__ void prefix_k(const int* __restrict__ topki,
                         const float* __restrict__ blockpart, int* base,
                         int* total, int* cursor, void* out, const int* flag) {
    __shared__ int hist[NE];
    __shared__ float psum[NE];
    int tid = threadIdx.x;
    if (tid < NE) { hist[tid] = 0; psum[tid] = 0.f; }
    __syncthreads();
    for (int i = tid; i < TT * KTOP; i += 256) atomicAdd(&hist[topki[i] & 7], 1);
    for (int i = tid; i < RBLK * NE; i += 256) atomicAdd(&psum[i & 7], blockpart[i]);
    __syncthreads();
    if (tid == 0) {
        int cum = 0; float aux = 0.f;
        for (int e = 0; e < NE; ++e) {
            int c = hist[e];
            base[e] = cum; cum += (c + 63) & ~63;
            cursor[e] = 0;
            aux += ((float)c / (float)(TT * KTOP)) * (psum[e] / (float)TT);
        }
        *total = cum;
        float auxv = aux * (float)NE * 0.01f;
        if (*flag) ((u16*)out)[(size_t)TT * HD] = f2b(auxv);
        else       ((float*)out)[(size_t)TT * HD] = auxv;
    }
}

// ---- scatter: two-level counting sort (LDS local, 8 global atomics/blk) ----
__global__ void scatter_k(const int* __restrict__ topki, const float* __restrict__ topkp,
                          const int* __restrict__ base, int* cursor,
                          int* tokof, float* pslot, int* slotmap) {
    __shared__ int lcnt[NE], lbase[NE];
    int tid = threadIdx.x;
    int t = blockIdx.x * 256 + tid;
    if (tid < NE) lcnt[tid] = 0;
    __syncthreads();
    int e0 = topki[2 * t] & 7, e1 = topki[2 * t + 1] & 7;
    float q0 = topkp[2 * t], q1 = topkp[2 * t + 1];
    int l0 = atomicAdd(&lcnt[e0], 1);
    int l1 = atomicAdd(&lcnt[e1], 1);
    __syncthreads();
    if (tid < NE) lbase[tid] = atomicAdd(&cursor[tid], lcnt[tid]);
    __syncthreads();
    int s0 = min(max(base[e0] + lbase[e0] + l0, 0), SLOTS - 1);
    int s1 = min(max(base[e1] + lbase[e1] + l1, 0), SLOTS - 1);
    tokof[s0] = t;  pslot[s0] = q0;  slotmap[2 * t] = s0;
    tokof[s1] = t;  pslot[s1] = q1;  slotmap[2 * t + 1] = s1;
}

// ---- GEMM1: act = silu(X Wg) * (X Wu); 64x64 tile, 4 waves of 32x32 ----
__global__ __launch_bounds__(256) void gemm1_k(
        const u16* __restrict__ xb, const u16* __restrict__ wgt,
        const u16* __restrict__ wut, const int* __restrict__ base,
        const int* __restrict__ total, const int* __restrict__ tokof,
        u16* __restrict__ act) {
    __shared__ u16 As[64][72], Bg[64][72], Bu[64][72];
    int row0 = blockIdx.y * 64;
    if (row0 >= *total) return;
    int e = 7;
    while (e > 0 && row0 < base[e]) --e;
    int n0 = blockIdx.x * 64;
    int tid = threadIdx.x;
    int r = tid >> 2, cg = (tid & 3) * 8;
    int tok = tokof[row0 + r];
    bool tv = ((unsigned)tok < (unsigned)TT);
    const u16* xrow = xb + (size_t)(tv ? tok : 0) * HD;
    const u16* bgrow = wgt + ((size_t)e * ID + n0 + r) * HD;
    const u16* burow = wut + ((size_t)e * ID + n0 + r) * HD;
    int wave = tid >> 6, lane = tid & 63;
    int wm = (wave & 1) * 32, wn = (wave >> 1) * 32;
    int lhi = (lane >> 4) * 8, llo = lane & 15;
    floatx4 accG[2][2], accU[2][2];
#pragma unroll
    for (int i = 0; i < 2; ++i)
#pragma unroll
        for (int j = 0; j < 2; ++j) {
            accG[i][j] = floatx4{0.f, 0.f, 0.f, 0.f};
            accU[i][j] = floatx4{0.f, 0.f, 0.f, 0.f};
        }
    uint4 z4 = make_uint4(0, 0, 0, 0);
    for (int k0 = 0; k0 < HD; k0 += 64) {
        uint4 a1 = z4, a2 = z4;
        if (tv) {
            a1 = *(const uint4*)&xrow[k0 + cg];
            a2 = *(const uint4*)&xrow[k0 + cg + 32];
        }
        uint4 g1 = *(const uint4*)&bgrow[k0 + cg];
        uint4 g2 = *(const uint4*)&bgrow[k0 + cg + 32];
        uint4 u1 = *(const uint4*)&burow[k0 + cg];
        uint4 u2 = *(const uint4*)&burow[k0 + cg + 32];
        __syncthreads();
        *(uint4*)&As[r][cg] = a1; *(uint4*)&As[r][cg + 32] = a2;
        *(uint4*)&Bg[r][cg] = g1; *(uint4*)&Bg[r][cg + 32] = g2;
        *(uint4*)&Bu[r][cg] = u1; *(uint4*)&Bu[r][cg + 32] = u2;
        __syncthreads();
#pragma unroll
        for (int kk = 0; kk < 64; kk += 32) {
            bhalf8 a0 = *(const bhalf8*)&As[wm + llo][kk + lhi];
            bhalf8 a1f = *(const bhalf8*)&As[wm + 16 + llo][kk + lhi];
            bhalf8 b0 = *(const bhalf8*)&Bg[wn + llo][kk + lhi];
            bhalf8 b1 = *(const bhalf8*)&Bg[wn + 16 + llo][kk + lhi];
            bhalf8 c0 = *(const bhalf8*)&Bu[wn + llo][kk + lhi];
            bhalf8 c1 = *(const bhalf8*)&Bu[wn + 16 + llo][kk + lhi];
            accG[0][0] = __builtin_amdgcn_mfma_f32_16x16x32_bf16(a0, b0, accG[0][0], 0, 0, 0);
            accG[0][1] = __builtin_amdgcn_mfma_f32_16x16x32_bf16(a0, b1, accG[0][1], 0, 0, 0);
            accG[1][0] = __builtin_amdgcn_mfma_f32_16x16x32_bf16(a1f, b0, accG[1][0], 0, 0, 0);
            accG[1][1] = __builtin_amdgcn_mfma_f32_16x16x32_bf16(a1f, b1, accG[1][1], 0, 0, 0);
            accU[0][0] = __builtin_amdgcn_mfma_f32_16x16x32_bf16(a0, c0, accU[0][0], 0, 0, 0);
            accU[0][1] = __builtin_amdgcn_mfma_f32_16x16x32_bf16(a0, c1, accU[0][1], 0, 0, 0);
            accU[1][0] = __builtin_amdgcn_mfma_f32_16x16x32_bf16(a1f, c0, accU[1][0], 0, 0, 0);
            accU[1][1] = __builtin_amdgcn_mfma_f32_16x16x32_bf16(a1f, c1, accU[1][1], 0, 0, 0);
        }
    }
    int mrow = (lane >> 4) * 4;  // C/D: col=lane&15, row=(lane>>4)*4+reg
#pragma unroll
    for (int i = 0; i < 2; ++i)
#pragma unroll
        for (int j = 0; j < 2; ++j)
#pragma unroll
            for (int rr = 0; rr < 4; ++rr) {
                int m = row0 + wm + i * 16 + mrow + rr;
                int n = n0 + wn + j * 16 + llo;
                float g = accG[i][j][rr], u = accU[i][j][rr];
                float sv = g / (1.f + expf(-g));
                act[(size_t)m * ID + n] = f2b(sv * u);
            }
}

// ---- GEMM2: y = p * (act Wd), fp32 out ----
__global__ __launch_bounds__(256) void gemm2_k(
        const u16* __restrict__ act, const u16* __restrict__ wdt,
        const int* __restrict__ base, const int* __restrict__ total,
        const float* __restrict__ pslot, float* __restrict__ y) {
    __shared__ u16 As[64][72], Bs[64][72];
    int row0 = blockIdx.y * 64;
    if (row0 >= *total) return;
    int e = 7;
    while (e > 0 && row0 < base[e]) --e;
    int n0 = blockIdx.x * 64;
    int tid = threadIdx.x;
    int r = tid >> 2, cg = (tid & 3) * 8;
    const u16* arow = act + (size_t)(row0 + r) * ID;
    const u16* brow = wdt + ((size_t)e * HD + n0 + r) * ID;
    int wave = tid >> 6, lane = tid & 63;
    int wm = (wave & 1) * 32, wn = (wave >> 1) * 32;
    int lhi = (lane >> 4) * 8, llo = lane & 15;
    floatx4 acc[2][2];
#pragma unroll
    for (int i = 0; i < 2; ++i)
#pragma unroll
        for (int j = 0; j < 2; ++j) acc[i][j] = floatx4{0.f, 0.f, 0.f, 0.f};
    for (int k0 = 0; k0 < ID; k0 += 64) {
        uint4 a1 = *(const uint4*)&arow[k0 + cg];
        uint4 a2 = *(const uint4*)&arow[k0 + cg + 32];
        uint4 b1 = *(const uint4*)&brow[k0 + cg];
        uint4 b2 = *(const uint4*)&brow[k0 + cg + 32];
        __syncthreads();
        *(uint4*)&As[r][cg] = a1; *(uint4*)&As[r][cg + 32] = a2;
        *(uint4*)&Bs[r][cg] = b1; *(uint4*)&Bs[r][cg + 32] = b2;
        __syncthreads();
#pragma unroll
        for (int kk = 0; kk < 64; kk += 32) {
            bhalf8 a0 = *(const bhalf8*)&As[wm + llo][kk + lhi];
            bhalf8 a1f = *(const bhalf8*)&As[wm + 16 + llo][kk + lhi];
            bhalf8 b0 = *(const bhalf8*)&Bs[wn + llo][kk + lhi];
            bhalf8 b1f = *(const bhalf8*)&Bs[wn + 16 + llo][kk + lhi];
            acc[0][0] = __builtin_amdgcn_mfma_f32_16x16x32_bf16(a0, b0, acc[0][0], 0, 0, 0);
            acc[0][1] = __builtin_amdgcn_mfma_f32_16x16x32_bf16(a0, b1f, acc[0][1], 0, 0, 0);
            acc[1][0] = __builtin_amdgcn_mfma_f32_16x16x32_bf16(a1f, b0, acc[1][0], 0, 0, 0);
            acc[1][1] = __builtin_amdgcn_mfma_f32_16x16x32_bf16(a1f, b1f, acc[1][1], 0, 0, 0);
        }
    }
    int mrow = (lane >> 4) * 4;
#pragma unroll
    for (int i = 0; i < 2; ++i)
#pragma unroll
        for (int j = 0; j < 2; ++j)
#pragma unroll
            for (int rr = 0; rr < 4; ++rr) {
                int m = row0 + wm + i * 16 + mrow + rr;
                int n = n0 + wn + j * 16 + llo;
                float p = pslot[m];  // 0 for padded rows
                y[(size_t)m * HD + n] = p * acc[i][j][rr];
            }
}

// ---- combine the two expert slots per token; dtype-flagged output ----
__global__ void combine_k(const float* __restrict__ y, const int* __restrict__ slotmap,
                          void* __restrict__ out, const int* __restrict__ flag) {
    int g = blockIdx.x * 256 + threadIdx.x;  // TT*192 quads
    int t = g / 192;
    int q = (g % 192) * 4;
    int s0 = slotmap[2 * t], s1 = slotmap[2 * t + 1];
    s0 = min(max(s0, 0), SLOTS - 1);
    s1 = min(max(s1, 0), SLOTS - 1);
    float4 a = *(const float4*)&y[(size_t)s0 * HD + q];
    float4 b = *(const float4*)&y[(size_t)s1 * HD + q];
    float4 rv;
    rv.x = a.x + b.x; rv.y = a.y + b.y; rv.z = a.z + b.z; rv.w = a.w + b.w;
    if (*flag) {
        ushort4 o;
        o.x = f2b(rv.x); o.y = f2b(rv.y); o.z = f2b(rv.z); o.w = f2b(rv.w);
        *(ushort4*)((u16*)out + (size_t)t * HD + q) = o;
    } else {
        *(float4*)((float*)out + (size_t)t * HD + q) = rv;
    }
}

extern "C" void kernel_launch(void* const* d_in, const int* in_sizes, int n_in,
                              void* d_out, int out_size, void* d_ws, size_t ws_size,
                              hipStream_t stream) {
    const void* x  = d_in[0];
    const void* rw = d_in[1];
    const void* wg = d_in[2];
    const void* wu = d_in[3];
    const void* wd = d_in[4];
    char* ws = (char*)d_ws;

    // workspace layout (bytes)
    int*   hdr     = (int*)(ws + 0);          // cnt[8],cursor[8],base[8],total,probsum[8]
    int*   cursor  = (int*)(ws + 32);
    int*   base    = (int*)(ws + 64);
    int*   total   = (int*)(ws + 96);
    int*   flag    = (int*)(ws + 224);
    int*   topki   = (int*)(ws + 256);        // [4096]
    float* topkp   = (float*)(ws + 16640);    // [4096]
    int*   tokof   = (int*)(ws + 33024);      // [4608]
    float* pslot   = (float*)(ws + 51456);    // [4608]
    int*   slotmap = (int*)(ws + 69888);      // [4096]
    float* blockpart = (float*)(ws + 86272);  // [512*8] router partials
    u16*   xb      = (u16*)(ws + 102656);     // [2048*768] bf16
    u16*   act     = (u16*)(ws + 3248384);    // [4608*1536] bf16
    float* ybuf    = (float*)(ws + 17404160); // [4608*768] fp32
    u16*   wgt     = (u16*)(ws + 31559936);   // [8][1536][768] bf16
    u16*   wut     = (u16*)(ws + 50434304);
    u16*   wdt     = (u16*)(ws + 69308672);   // [8][768][1536] bf16
    if (ws_size < 88183040u) return;  // clean absmax-fail beats a wild write

    init_k<<<18, 256, 0, stream>>>((const u16*)x, flag, hdr, tokof, pslot);
    xcvt_k<<<(TT * HD / 8) / 256, 256, 0, stream>>>(x, xb, flag);
    cvtT_k<<<dim3(ID / 64, HD / 64, 2 * NE), 256, 0, stream>>>(wg, wu, wgt, wut,
                                                               HD, ID, flag);
    cvtT_k<<<dim3(HD / 64, ID / 64, NE), 256, 0, stream>>>(wd, nullptr, wdt, nullptr,
                                                           ID, HD, flag);
    router_k<<<RBLK, 256, 0, stream>>>(x, rw, flag, topki, topkp, blockpart);
    prefix_k<<<1, 256, 0, stream>>>(topki, blockpart, base, total, cursor, d_out, flag);
    scatter_k<<<TT / 256, 256, 0, stream>>>(topki, topkp, base, cursor,
                                            tokof, pslot, slotmap);
    gemm1_k<<<dim3(ID / 64, SLOTS / 64), 256, 0, stream>>>(xb, wgt, wut, base, total,
                                                           tokof, act);
    gemm2_k<<<dim3(HD / 64, SLOTS / 64), 256, 0, stream>>>(act, wdt, base, total,
                                                           pslot, ybuf);
    combine_k<<<(TT * 192) / 256, 256, 0, stream>>>(ybuf, slotmap, d_out, flag);
}

// Round 5
// 266.814 us; speedup vs baseline: 1.8589x; 1.0140x over previous
//
#include <hip/hip_runtime.h>
#include <math.h>

// ---------------------------------------------------------------------------
// MoE top-2/8, H=768, I=1536, T=2048. bf16 MFMA 16x16x32, fp32 accum.
// R4/R5: tile-packed swizzled operands + global_load_lds staging + 128x128
// blocks (64x64/wave). All operand tiles are 128 rows x 64 k bf16 = 16 KB,
// stored exactly as the LDS image with chunk swizzle pc = q ^ (row&7):
// verbatim 16B/lane DMA staging AND near-floor b128 fragment reads.
//   init -> router -> prefix(pad128) -> scatter -> apack(gather+cvt) ->
//   wpack(g,u) -> wpack(d) -> gemm1 -> gemm2 -> combine
// ---------------------------------------------------------------------------

typedef unsigned short u16;
typedef __attribute__((ext_vector_type(8))) short bhalf8;   // 8 bf16
typedef __attribute__((ext_vector_type(4))) float floatx4;  // MFMA C/D

#define HD 768
#define ID 1536
#define NE 8
#define TT 2048
#define SLOTS 5120   // 4096 assignments + per-expert pad to 128
#define MT 40        // max m-tiles (SLOTS/128)
#define RBLK 512

__device__ __forceinline__ float b2f(u16 u) {
    union { unsigned int i; float f; } v; v.i = ((unsigned int)u) << 16; return v.f;
}
__device__ __forceinline__ u16 f2b(float f) {
    union { float f; unsigned int i; } v; v.f = f;
    unsigned int i = v.i;
    return (u16)((i + 0x7FFFu + ((i >> 16) & 1u)) >> 16);  // RNE
}
// async global->LDS, 16B per lane; LDS dest = wave-uniform base + lane*16
__device__ __forceinline__ void glds16(const u16* g, u16* l) {
    __builtin_amdgcn_global_load_lds(
        (const __attribute__((address_space(1))) unsigned int*)g,
        (__attribute__((address_space(3))) unsigned int*)l, 16, 0, 0);
}

// ---- init + dtype sniff ----
__global__ void init_k(const u16* __restrict__ x16, int* flag,
                       int* hdr, int* tokof, float* pslot) {
    int i = blockIdx.x * 256 + threadIdx.x;
    if (i < 40) hdr[i] = 0;
    if (i < SLOTS) { tokof[i] = -1; pslot[i] = 0.f; }
    if (blockIdx.x == 0 && threadIdx.x >= 64 && threadIdx.x < 128) {
        int lane = threadIdx.x - 64, c = 0;
#pragma unroll
        for (int j = 0; j < 4; ++j) {
            u16 w = x16[lane + 64 * j];
            int ex = (w >> 7) & 0xFF;
            c += (ex >= 118 && ex <= 135);  // bf16 ~255/256 hit, fp32 ~136
        }
#pragma unroll
        for (int off = 32; off > 0; off >>= 1) c += __shfl_xor(c, off);
        if (lane == 0) *flag = (c >= 200) ? 1 : 0;
    }
}

// ---- router: one wave/token, block partials, no contended atomics ----
__global__ void router_k(const void* __restrict__ x, const void* __restrict__ rw,
                         const int* __restrict__ flag,
                         int* topki, float* topkp, float* blockpart) {
    __shared__ float sp[4][NE];
    int lane = threadIdx.x & 63, wave = threadIdx.x >> 6;
    int t = blockIdx.x * 4 + wave;
    int bf = *flag;
    const float* xf = (const float*)x + (size_t)t * HD;
    const u16*   xh = (const u16*)x + (size_t)t * HD;
    const float* rf = (const float*)rw;
    const u16*   rh = (const u16*)rw;
    float acc[NE];
#pragma unroll
    for (int e = 0; e < NE; ++e) acc[e] = 0.f;
    for (int j = 0; j < HD / 64; ++j) {
        int h = lane + 64 * j;
        float xv = bf ? b2f(xh[h]) : xf[h];
#pragma unroll
        for (int e = 0; e < NE; ++e)
            acc[e] += xv * (bf ? b2f(rh[h * NE + e]) : rf[h * NE + e]);
    }
#pragma unroll
    for (int e = 0; e < NE; ++e) {
        float v = acc[e];
#pragma unroll
        for (int off = 32; off > 0; off >>= 1) v += __shfl_xor(v, off);
        acc[e] = v;
    }
    if (lane == 0) {
        float m = acc[0];
        for (int e = 1; e < NE; ++e) m = fmaxf(m, acc[e]);
        float p[NE], s = 0.f;
        for (int e = 0; e < NE; ++e) { p[e] = expf(acc[e] - m); s += p[e]; }
        float inv = 1.f / s;
        for (int e = 0; e < NE; ++e) { p[e] *= inv; sp[wave][e] = p[e]; }
        int i1 = 0; float p1 = p[0];
        for (int e = 1; e < NE; ++e) if (p[e] > p1) { p1 = p[e]; i1 = e; }
        int i2 = -1; float p2 = -1.f;
        for (int e = 0; e < NE; ++e) if (e != i1 && p[e] > p2) { p2 = p[e]; i2 = e; }
        if (i2 < 0) { i2 = (i1 + 1) & 7; p2 = p[i2]; }  // NaN guard
        float sn = 1.f / (p1 + p2);
        topki[2 * t] = i1;  topki[2 * t + 1] = i2;
        topkp[2 * t] = p1 * sn;  topkp[2 * t + 1] = p2 * sn;
    }
    __syncthreads();
    if (threadIdx.x < NE)
        blockpart[blockIdx.x * NE + threadIdx.x] =
            sp[0][threadIdx.x] + sp[1][threadIdx.x] +
            sp[2][threadIdx.x] + sp[3][threadIdx.x];
}

// ---- prefix: histogram + bases (pad 128) + aux loss (1 block) ----
__global__ void prefix_k(const int* __restrict__ topki,
                         const float* __restrict__ blockpart, int* base,
                         int* total, int* cursor, void* out, const int* flag) {
    __shared__ int hist[NE];
    __shared__ float psum[NE];
    int tid = threadIdx.x;
    if (tid < NE) { hist[tid] = 0; psum[tid] = 0.f; }
    __syncthreads();
    for (int i = tid; i < TT * 2; i += 256) atomicAdd(&hist[topki[i] & 7], 1);
    for (int i = tid; i < RBLK * NE; i += 256) atomicAdd(&psum[i & 7], blockpart[i]);
    __syncthreads();
    if (tid == 0) {
        int cum = 0; float aux = 0.f;
        for (int e = 0; e < NE; ++e) {
            int c = hist[e];
            base[e] = cum; cum += (c + 127) & ~127;
            cursor[e] = 0;
            aux += ((float)c / (float)(TT * 2)) * (psum[e] / (float)TT);
        }
        *total = cum;
        float auxv = aux * (float)NE * 0.01f;
        if (*flag) ((u16*)out)[(size_t)TT * HD] = f2b(auxv);
        else       ((float*)out)[(size_t)TT * HD] = auxv;
    }
}

// ---- scatter: LDS counting sort, 8 global atomics per block ----
__global__ void scatter_k(const int* __restrict__ topki, const float* __restrict__ topkp,
                          const int* __restrict__ base, int* cursor,
                          int* tokof, float* pslot, int* slotmap) {
    __shared__ int lcnt[NE], lbase[NE];
    int tid = threadIdx.x;
    int t = blockIdx.x * 256 + tid;
    if (tid < NE) lcnt[tid] = 0;
    __syncthreads();
    int e0 = topki[2 * t] & 7, e1 = topki[2 * t + 1] & 7;
    float q0 = topkp[2 * t], q1 = topkp[2 * t + 1];
    int l0 = atomicAdd(&lcnt[e0], 1);
    int l1 = atomicAdd(&lcnt[e1], 1);
    __syncthreads();
    if (tid < NE) lbase[tid] = atomicAdd(&cursor[tid], lcnt[tid]);
    __syncthreads();
    int s0 = min(max(base[e0] + lbase[e0] + l0, 0), SLOTS - 1);
    int s1 = min(max(base[e1] + lbase[e1] + l1, 0), SLOTS - 1);
    tokof[s0] = t;  pslot[s0] = q0;  slotmap[2 * t] = s0;
    tokof[s1] = t;  pslot[s1] = q1;  slotmap[2 * t + 1] = s1;
}

// ---- apack: gather token rows -> packed swizzled A tiles [mt][kt][16KB] ----
__global__ void apack_k(const void* __restrict__ x, const int* __restrict__ flag,
                        const int* __restrict__ tokof, const int* __restrict__ total,
                        u16* __restrict__ apack) {
    int mt = blockIdx.y, kt = blockIdx.x;
    if (mt * 128 >= *total) return;
    int tid = threadIdx.x;
    int ml = tid >> 1, half = tid & 1;  // row in tile, 32-k half
    int tok = tokof[mt * 128 + ml];
    union { uint4 v[4]; u16 u[32]; } buf;
    if ((unsigned)tok < (unsigned)TT) {
        if (*flag) {
            const u16* s = (const u16*)x + (size_t)tok * HD + kt * 64 + half * 32;
#pragma unroll
            for (int c = 0; c < 4; ++c) buf.v[c] = *(const uint4*)&s[c * 8];
        } else {
            const float* s = (const float*)x + (size_t)tok * HD + kt * 64 + half * 32;
#pragma unroll
            for (int c = 0; c < 8; ++c) {
                float4 f = *(const float4*)&s[c * 4];
                buf.u[c * 4 + 0] = f2b(f.x); buf.u[c * 4 + 1] = f2b(f.y);
                buf.u[c * 4 + 2] = f2b(f.z); buf.u[c * 4 + 3] = f2b(f.w);
            }
        }
    } else {
#pragma unroll
        for (int c = 0; c < 4; ++c) buf.v[c] = make_uint4(0, 0, 0, 0);
    }
    u16* dst = apack + (((size_t)mt * 12 + kt) << 13) + ml * 64;
#pragma unroll
    for (int c = 0; c < 4; ++c) {
        int pc = (half * 4 + c) ^ (ml & 7);  // swizzled chunk
        *(uint4*)(dst + pc * 8) = buf.v[c];
    }
}

// ---- wpack: W [e][K][N] -> packed swizzled B tiles [e][nt][kt][16KB] ----
__global__ void wpack_k(const void* __restrict__ srcA, const void* __restrict__ srcB,
                        u16* __restrict__ dstA, u16* __restrict__ dstB,
                        int K, int N, int ktiles, int ntiles,
                        const int* __restrict__ flag) {
    __shared__ u16 t[8192];
    int z = blockIdx.z;
    const void* src = (srcB != nullptr && z >= NE) ? srcB : srcA;
    u16* dst = (dstB != nullptr && z >= NE) ? dstB : dstA;
    int e = z & 7;
    int kt = blockIdx.x, nt = blockIdx.y;
    int tid = threadIdx.x;
    int kr = tid >> 2, ng = (tid & 3) * 32;  // k-row, 32 n's
    size_t srow = ((size_t)e * K + (size_t)kt * 64 + kr) * N + (size_t)nt * 128 + ng;
    union { uint4 v[4]; u16 u[32]; } buf;
    if (*flag) {
        const u16* s = (const u16*)src + srow;
#pragma unroll
        for (int c = 0; c < 4; ++c) buf.v[c] = *(const uint4*)&s[c * 8];
    } else {
        const float* s = (const float*)src + srow;
#pragma unroll
        for (int c = 0; c < 8; ++c) {
            float4 f = *(const float4*)&s[c * 4];
            buf.u[c * 4 + 0] = f2b(f.x); buf.u[c * 4 + 1] = f2b(f.y);
            buf.u[c * 4 + 2] = f2b(f.z); buf.u[c * 4 + 3] = f2b(f.w);
        }
    }
#pragma unroll
    for (int jj = 0; jj < 32; ++jj) {
        int n = ng + jj;
        t[n * 64 + (((kr >> 3) ^ (n & 7)) << 3) + (kr & 7)] = buf.u[jj];
    }
    __syncthreads();
    u16* d = dst + ((((size_t)e * ntiles + nt) * ktiles + kt) << 13);
#pragma unroll
    for (int i = 0; i < 4; ++i) {
        int off = tid * 8 + i * 2048;
        *(uint4*)(d + off) = *(const uint4*)&t[off];
    }
}

// ---- GEMM1: act = silu(A Wg) * (A Wu); 128x128 block, 64x64/wave ----
__global__ __launch_bounds__(256, 2) void gemm1_k(
        const u16* __restrict__ apack, const u16* __restrict__ wgp,
        const u16* __restrict__ wup, const int* __restrict__ base,
        const int* __restrict__ total, u16* __restrict__ actp) {
    __shared__ u16 smem[24576];  // As 8192 u16 | Bg 8192 | Bu 8192
    u16* As = smem; u16* Bg = smem + 8192; u16* Bu = smem + 16384;
    int mt = blockIdx.y;
    if (mt * 128 >= *total) return;
    int e = 7;
    while (e > 0 && mt * 128 < base[e]) --e;
    int nt = blockIdx.x;
    int tid = threadIdx.x, lane = tid & 63, wave = tid >> 6;
    int wm = (wave & 1) * 64, wn = (wave >> 1) * 64;
    int llo = lane & 15, lq = lane >> 4;
    const u16* atile = apack + (((size_t)mt * 12) << 13);
    const u16* gtile = wgp + ((((size_t)e * 12 + nt) * 12) << 13);
    const u16* utile = wup + ((((size_t)e * 12 + nt) * 12) << 13);
    floatx4 accG[4][4], accU[4][4];
#pragma unroll
    for (int i = 0; i < 4; ++i)
#pragma unroll
        for (int j = 0; j < 4; ++j) {
            accG[i][j] = floatx4{0.f, 0.f, 0.f, 0.f};
            accU[i][j] = floatx4{0.f, 0.f, 0.f, 0.f};
        }
    for (int kt = 0; kt < 12; ++kt) {
        const u16* ga = atile + (kt << 13);
        const u16* gg = gtile + (kt << 13);
        const u16* gu = utile + (kt << 13);
        __syncthreads();  // previous compute done before DMA overwrites
#pragma unroll
        for (int i = 0; i < 4; ++i) {
            int off = tid * 8 + i * 2048;
            glds16(ga + off, As + off);
            glds16(gg + off, Bg + off);
            glds16(gu + off, Bu + off);
        }
        asm volatile("s_waitcnt vmcnt(0)" ::: "memory");
        __syncthreads();
#pragma unroll
        for (int kk = 0; kk < 2; ++kk) {
            int q = kk * 4 + lq;  // logical k-chunk
            bhalf8 af[4], bg[4], bu[4];
#pragma unroll
            for (int i = 0; i < 4; ++i) {
                int m = wm + i * 16 + llo;
                af[i] = *(const bhalf8*)&As[m * 64 + ((q ^ (m & 7)) << 3)];
                int n = wn + i * 16 + llo;
                bg[i] = *(const bhalf8*)&Bg[n * 64 + ((q ^ (n & 7)) << 3)];
                bu[i] = *(const bhalf8*)&Bu[n * 64 + ((q ^ (n & 7)) << 3)];
            }
#pragma unroll
            for (int i = 0; i < 4; ++i)
#pragma unroll
                for (int j = 0; j < 4; ++j) {
                    accG[i][j] = __builtin_amdgcn_mfma_f32_16x16x32_bf16(af[i], bg[j], accG[i][j], 0, 0, 0);
                    accU[i][j] = __builtin_amdgcn_mfma_f32_16x16x32_bf16(af[i], bu[j], accU[i][j], 0, 0, 0);
                }
        }
    }
    // epilogue: silu(g)*u -> LDS [128][128] -> packed swizzled act tiles
    __syncthreads();
    u16* Ah = smem;  // 16384 u16 = 32 KB
    int q4 = lq * 4;
#pragma unroll
    for (int i = 0; i < 4; ++i)
#pragma unroll
        for (int j = 0; j < 4; ++j)
#pragma unroll
            for (int rr = 0; rr < 4; ++rr) {
                int m = wm + i * 16 + q4 + rr;
                int n = wn + j * 16 + llo;
                float g = accG[i][j][rr], u = accU[i][j][rr];
                Ah[m * 128 + n] = f2b((g / (1.f + expf(-g))) * u);
            }
    __syncthreads();
    u16* dst = actp + (((size_t)mt * 24 + nt * 2) << 13);
#pragma unroll
    for (int s = 0; s < 2; ++s)
#pragma unroll
        for (int i = 0; i < 4; ++i) {
            int off = tid * 8 + i * 2048;   // u16 offset in 16KB subtile
            int m = off >> 6;
            int pc = (off >> 3) & 7;
            int q = pc ^ (m & 7);
            *(uint4*)(dst + ((size_t)s << 13) + off) =
                *(const uint4*)&Ah[m * 128 + s * 64 + q * 8];
        }
}

// ---- GEMM2: y = pslot * (act Wd); 128x128 block, 64x64/wave ----
__global__ __launch_bounds__(256, 2) void gemm2_k(
        const u16* __restrict__ actp, const u16* __restrict__ wdp,
        const int* __restrict__ base, const int* __restrict__ total,
        const float* __restrict__ pslot, float* __restrict__ y) {
    __shared__ u16 smem[16384];  // As 8192 | Bs 8192
    u16* As = smem; u16* Bs = smem + 8192;
    int mt = blockIdx.y;
    if (mt * 128 >= *total) return;
    int e = 7;
    while (e > 0 && mt * 128 < base[e]) --e;
    int nt = blockIdx.x;  // 0..5
    int tid = threadIdx.x, lane = tid & 63, wave = tid >> 6;
    int wm = (wave & 1) * 64, wn = (wave >> 1) * 64;
    int llo = lane & 15, lq = lane >> 4;
    const u16* atile = actp + (((size_t)mt * 24) << 13);
    const u16* btile = wdp + ((((size_t)e * 6 + nt) * 24) << 13);
    floatx4 acc[4][4];
#pragma unroll
    for (int i = 0; i < 4; ++i)
#pragma unroll
        for (int j = 0; j < 4; ++j) acc[i][j] = floatx4{0.f, 0.f, 0.f, 0.f};
    for (int kt = 0; kt < 24; ++kt) {
        const u16* ga = atile + (kt << 13);
        const u16* gb = btile + (kt << 13);
        __syncthreads();
#pragma unroll
        for (int i = 0; i < 4; ++i) {
            int off = tid * 8 + i * 2048;
            glds16(ga + off, As + off);
            glds16(gb + off, Bs + off);
        }
        asm volatile("s_waitcnt vmcnt(0)" ::: "memory");
        __syncthreads();
#pragma unroll
        for (int kk = 0; kk < 2; ++kk) {
            int q = kk * 4 + lq;
            bhalf8 af[4], bf[4];
#pragma unroll
            for (int i = 0; i < 4; ++i) {
                int m = wm + i * 16 + llo;
                af[i] = *(const bhalf8*)&As[m * 64 + ((q ^ (m & 7)) << 3)];
                int n = wn + i * 16 + llo;
                bf[i] = *(const bhalf8*)&Bs[n * 64 + ((q ^ (n & 7)) << 3)];
            }
#pragma unroll
            for (int i = 0; i < 4; ++i)
#pragma unroll
                for (int j = 0; j < 4; ++j)
                    acc[i][j] = __builtin_amdgcn_mfma_f32_16x16x32_bf16(af[i], bf[j], acc[i][j], 0, 0, 0);
        }
    }
    int q4 = lq * 4;
#pragma unroll
    for (int i = 0; i < 4; ++i)
#pragma unroll
        for (int rr = 0; rr < 4; ++rr) {
            int m = mt * 128 + wm + i * 16 + q4 + rr;
            float p = pslot[m];
#pragma unroll
            for (int j = 0; j < 4; ++j) {
                int n = nt * 128 + wn + j * 16 + llo;
                y[(size_t)m * HD + n] = p * acc[i][j][rr];
            }
        }
}

// ---- combine two expert slots per token ----
__global__ void combine_k(const float* __restrict__ y, const int* __restrict__ slotmap,
                          void* __restrict__ out, const int* __restrict__ flag) {
    int g = blockIdx.x * 256 + threadIdx.x;  // TT*192 quads
    int t = g / 192;
    int q = (g % 192) * 4;
    int s0 = min(max(slotmap[2 * t], 0), SLOTS - 1);
    int s1 = min(max(slotmap[2 * t + 1], 0), SLOTS - 1);
    float4 a = *(const float4*)&y[(size_t)s0 * HD + q];
    float4 b = *(const float4*)&y[(size_t)s1 * HD + q];
    float4 rv;
    rv.x = a.x + b.x; rv.y = a.y + b.y; rv.z = a.z + b.z; rv.w = a.w + b.w;
    if (*flag) {
        ushort4 o;
        o.x = f2b(rv.x); o.y = f2b(rv.y); o.z = f2b(rv.z); o.w = f2b(rv.w);
        *(ushort4*)((u16*)out + (size_t)t * HD + q) = o;
    } else {
        *(float4*)((float*)out + (size_t)t * HD + q) = rv;
    }
}

extern "C" void kernel_launch(void* const* d_in, const int* in_sizes, int n_in,
                              void* d_out, int out_size, void* d_ws, size_t ws_size,
                              hipStream_t stream) {
    const void* x  = d_in[0];
    const void* rw = d_in[1];
    const void* wg = d_in[2];
    const void* wu = d_in[3];
    const void* wd = d_in[4];
    char* ws = (char*)d_ws;

    // workspace layout (bytes), total 80,322,816:
    //   apack  @   106,752 + 7,864,320  ->  7,971,072   (40*12 tiles * 16 KB)
    //   actp   @ 7,971,072 + 15,728,640 -> 23,699,712   (40*24 tiles)
    //   wgp    @ 23,699,712 + 18,874,368 -> 42,574,080  (8*12*12 tiles)
    //   wup    @ 42,574,080 + 18,874,368 -> 61,448,448
    //   wdp    @ 61,448,448 + 18,874,368 -> 80,322,816  (8*6*24 tiles)
    //   ybuf   @ 23,699,712 (overlaps wgp/wup: SAFE — gemm1's last read of
    //            wgp/wup strictly precedes gemm2's first ybuf write in-stream)
    int*   hdr     = (int*)(ws + 0);
    int*   cursor  = (int*)(ws + 32);
    int*   base    = (int*)(ws + 64);
    int*   total   = (int*)(ws + 96);
    int*   flag    = (int*)(ws + 224);
    int*   topki   = (int*)(ws + 256);         // [4096]
    float* topkp   = (float*)(ws + 16640);     // [4096]
    int*   tokof   = (int*)(ws + 33024);       // [5120]
    float* pslot   = (float*)(ws + 53504);     // [5120]
    int*   slotmap = (int*)(ws + 73984);       // [4096]
    float* blockpart = (float*)(ws + 90368);   // [512*8]
    u16*   apack   = (u16*)(ws + 106752);
    u16*   actp    = (u16*)(ws + 7971072);
    u16*   wgp     = (u16*)(ws + 23699712);
    u16*   wup     = (u16*)(ws + 42574080);
    u16*   wdp     = (u16*)(ws + 61448448);
    float* ybuf    = (float*)(ws + 23699712);  // 5120*768*4 = 15.7 MB
    if (ws_size < 80322816u) return;  // clean absmax-fail beats a wild write

    init_k<<<20, 256, 0, stream>>>((const u16*)x, flag, hdr, tokof, pslot);
    router_k<<<RBLK, 256, 0, stream>>>(x, rw, flag, topki, topkp, blockpart);
    prefix_k<<<1, 256, 0, stream>>>(topki, blockpart, base, total, cursor, d_out, flag);
    scatter_k<<<TT / 256, 256, 0, stream>>>(topki, topkp, base, cursor,
                                            tokof, pslot, slotmap);
    apack_k<<<dim3(12, MT), 256, 0, stream>>>(x, flag, tokof, total, apack);
    wpack_k<<<dim3(12, 12, 16), 256, 0, stream>>>(wg, wu, wgp, wup,
                                                  HD, ID, 12, 12, flag);
    wpack_k<<<dim3(24, 6, 8), 256, 0, stream>>>(wd, nullptr, wdp, nullptr,
                                                ID, HD, 24, 6, flag);
    gemm1_k<<<dim3(12, MT), 256, 0, stream>>>(apack, wgp, wup, base, total, actp);
    gemm2_k<<<dim3(6, MT), 256, 0, stream>>>(actp, wdp, base, total, pslot, ybuf);
    combine_k<<<(TT * 192) / 256, 256, 0, stream>>>(ybuf, slotmap, d_out, flag);
}